// Round 4
// baseline (136.981 us; speedup 1.0000x reference)
//
#include <hip/hip_runtime.h>
#include <stdint.h>

typedef unsigned int u32;
typedef unsigned short u16;
typedef unsigned long long u64;
typedef __bf16 bf16x8 __attribute__((ext_vector_type(8)));
typedef float f32x4 __attribute__((ext_vector_type(4)));
typedef u32 u32x4 __attribute__((ext_vector_type(4)));

#define IN_DIM 512

__device__ __forceinline__ u16 bfr(float f) {
  __bf16 h = (__bf16)f;
  return __builtin_bit_cast(u16, h);
}
__device__ __forceinline__ u16 f2bf(float f) {
  u32 u = __builtin_bit_cast(u32, f);
  u += 0x7fffu + ((u >> 16) & 1u);
  return (u16)(u >> 16);
}
__device__ __forceinline__ u32 pk2(float a, float b) {
  return (u32)f2bf(a) | ((u32)f2bf(b) << 16);
}

// ---------------------------------------------------------------------------
// pack_b: B packed in MFMA-fragment order (L2->VGPR direct in the GEMM).
// Chunk(nbp, s, cb, ks) = 64 lanes x 16B; lane l holds
//   col = nbp*128 + cb*16 + (l&15), kexp = s*64 + ks*32 + (l>>4)*8 .. +7
// Per (col,dim) 16 slots: 0..12 coeffs, 13=W, 14=W, 15=0.
// ---------------------------------------------------------------------------
__global__ void pack_b(const float* __restrict__ coeffs,
                       const float* __restrict__ bw,
                       char* __restrict__ Bp) {
  __shared__ float stage[64][56];
  const int tid = threadIdx.x;
  const int q = tid & 3, g = tid >> 2;
  const int id = blockIdx.x * 64 + g;          // (col, s) pair
  const int col = id >> 7, s = id & 127;
  const float* cbase = coeffs + ((size_t)col * IN_DIM + s * 4) * 13;
#pragma unroll
  for (int j = 0; j < 3; ++j) {
    int ch = q + j * 4;
    float4 v = *(const float4*)(cbase + ch * 4);
    stage[g][ch * 4 + 0] = v.x; stage[g][ch * 4 + 1] = v.y;
    stage[g][ch * 4 + 2] = v.z; stage[g][ch * 4 + 3] = v.w;
  }
  if (q == 0) {
    float4 v = *(const float4*)(cbase + 48);
    stage[g][48] = v.x; stage[g][49] = v.y; stage[g][50] = v.z; stage[g][51] = v.w;
  }
  if (q == 1) {
    float4 v = *(const float4*)(bw + (size_t)col * IN_DIM + s * 4);
    stage[g][52] = v.x; stage[g][53] = v.y; stage[g][54] = v.z; stage[g][55] = v.w;
  }
  __syncthreads();
  const int nbp = col >> 7, cb = (col >> 4) & 7, cl = col & 15;
  char* base = Bp + (((size_t)(nbp * 128 + s) * 8 + cb) * 2) * 1024;
#pragma unroll
  for (int r = 0; r < 2; ++r) {
    int idx = q * 2 + r;
    int h = idx & 1;
    int dd = idx >> 1;              // dim-in-step 0..3
    int ks = dd >> 1;
    const float* sf = &stage[g][dd * 13];
    float w = stage[g][52 + dd];
    u16 hh[8];
#pragma unroll
    for (int c = 0; c < 8; ++c) {
      int slot = h * 8 + c;
      float v = slot < 13 ? sf[slot] : (slot < 15 ? w : 0.0f);
      hh[c] = bfr(v);
    }
    u32x4 o;
    o.x = (u32)hh[0] | ((u32)hh[1] << 16);
    o.y = (u32)hh[2] | ((u32)hh[3] << 16);
    o.z = (u32)hh[4] | ((u32)hh[5] << 16);
    o.w = (u32)hh[6] | ((u32)hh[7] << 16);
    int lanei = cl + 16 * (2 * (dd & 1) + h);
    *(u32x4*)(base + (size_t)ks * 1024 + lanei * 16) = o;
  }
}

// ---------------------------------------------------------------------------
// A expansion: one x -> 16 bf16 K-slots as two swizzled ds_write_b128.
// ---------------------------------------------------------------------------
__device__ __forceinline__ void expandA(float xv, char* rb, u32 swz, u32 k0) {
  float xc = fminf(fmaxf(xv, -0.9999f), 0.9999f);
  float tp = __fmaf_rn(xc, 2.5f, 3.0f);
  float fj = floorf(tp);
  int jl = (int)fj;  // 0..5
  float u = tp - fj;
  float u2 = u * u, u3 = u2 * u;
  float vv = 1.0f - u;
  float b0 = vv * vv * vv * (1.0f / 6.0f);
  float b3 = u3 * (1.0f / 6.0f);
  float b1 = __fmaf_rn(0.5f, u3, __fmaf_rn(u2, -1.0f, 2.0f / 3.0f));
  float b2 = 1.0f - b0 - b1 - b3;
  float e = __expf(-xv);
  float sg = __fdividef(xv, 1.0f + e);
  u16 sh = bfr(sg);
  float shf = __builtin_bit_cast(float, ((u32)sh) << 16);
  u16 sl = bfr(sg - shf);
  u32 pk01 = (u32)bfr(b0) | ((u32)bfr(b1) << 16);
  u32 pk23 = (u32)bfr(b2) | ((u32)bfr(b3) << 16);
  u64 v = (u64)pk01 | (((u64)pk23) << 32);
  int sstart = jl + 2;       // 2..7
  int qa = sstart >> 2;
  int shn = (sstart & 3) << 4;
  u64 lo = v << shn;
  u64 hi = shn ? (v >> (64 - shn)) : 0ull;
  u64 q0 = qa ? 0ull : lo;
  u64 q1 = qa ? lo : hi;
  u64 q2 = qa ? hi : 0ull;
  u64 q3 = (u64)(((u32)sh) << 16) | (((u64)(u32)sl) << 32);
  u32x4 c0, c1;
  c0.x = (u32)q0; c0.y = (u32)(q0 >> 32); c0.z = (u32)q1; c0.w = (u32)(q1 >> 32);
  c1.x = (u32)q2; c1.y = (u32)(q2 >> 32); c1.z = (u32)q3; c1.w = (u32)(q3 >> 32);
  *(u32x4*)(rb + ((k0 ^ swz) << 4)) = c0;
  *(u32x4*)(rb + (((k0 + 1u) ^ swz) << 4)) = c1;
}

// ---------------------------------------------------------------------------
// Main GEMM: BM=128, BN=64, grid 512 (2 blocks/CU -> 4 waves/SIMD).
// 8 waves = wm4 x wn1 x kt2; wave tile 32x64, acc 2x4.
// A through LDS (dbuf, 1 barrier/step); B-frags L2/L1 -> regs (reg dbuf).
// ---------------------------------------------------------------------------
__launch_bounds__(512, 4)
__global__ void kan_gemm(const float* __restrict__ x,
                         const char* __restrict__ Bp,
                         float* __restrict__ out) {
  __shared__ __align__(16) char smem[33792];  // A dbuf 2x16KB | red 128x66 f32

  const int tid = threadIdx.x;
  const int lane = tid & 63;
  const int wid = tid >> 6;
  const int kt = wid & 1;              // K-split team (ks slot)
  const int wm = wid >> 1;             // 0..3: 32-row group
  const int lrow = lane & 15, lkg = lane >> 4;

  const int bid = blockIdx.x;
  const int nb = bid & 7;              // nb == XCD: 1MB B panel stays in its L2
  const int mb = bid >> 3;             // 0..63

  // A expansion: 1 value/thread/step
  const int arow = tid >> 2, ad = tid & 3;
  const u32 aswz = (u32)(arow & 7);
  const u32 ak0 = (u32)(ad * 2);
  const float* xp = x + (size_t)(mb * 128 + arow) * IN_DIM + ad;

  // B-frag pointer: col group = nb*64 + fn*16 ; nbp = nb>>1, cb = (nb&1)*4+fn
  const char* bptr = Bp +
      ((((size_t)(nb >> 1) * 128) * 8 + (size_t)((nb & 1) * 4)) * 2 + (size_t)kt) * 1024 +
      (size_t)lane * 16;

  f32x4 acc[2][4];
#pragma unroll
  for (int i = 0; i < 2; ++i)
#pragma unroll
    for (int j = 0; j < 4; ++j) acc[i][j] = (f32x4){0.f, 0.f, 0.f, 0.f};

  u32x4 bA[4], bB[4];
  // prologue: expand step 0, load B-frags for step 0
  expandA(xp[0], smem + arow * 128, aswz, ak0);
#pragma unroll
  for (int fn = 0; fn < 4; ++fn)
    bA[fn] = *(const u32x4*)(bptr + fn * 2048);
  float xcur = xp[4];
  __syncthreads();

  const char* arb = smem + (wm * 32 + lrow) * 128;
  const u32 asl = (((u32)(kt * 4) | (u32)lkg) ^ (u32)(lrow & 7)) << 4;

#define GEMM_STEP(SN, NXT_OFF, CUR_OFF, BCUR, BNXT)                            \
  {                                                                            \
    int sl_ = (SN) < 128 ? (SN) : 127;                                         \
    _Pragma("unroll")                                                          \
    for (int fn = 0; fn < 4; ++fn)                                             \
      BNXT[fn] = *(const u32x4*)(bptr + (size_t)sl_ * 16384 + fn * 2048);      \
    float xnext = xp[((SN) + 1 < 128 ? (SN) + 1 : 127) * 4];                   \
    if ((SN) < 128) expandA(xcur, smem + (NXT_OFF) + arow * 128, aswz, ak0);   \
    xcur = xnext;                                                              \
    bf16x8 af[2];                                                              \
    _Pragma("unroll")                                                          \
    for (int fm = 0; fm < 2; ++fm)                                             \
      af[fm] = __builtin_bit_cast(bf16x8,                                      \
          *(const u32x4*)(arb + (CUR_OFF) + fm * 2048 + asl));                 \
    __builtin_amdgcn_s_setprio(1);                                             \
    _Pragma("unroll")                                                          \
    for (int fm = 0; fm < 2; ++fm)                                             \
      _Pragma("unroll")                                                        \
      for (int fn = 0; fn < 4; ++fn)                                           \
        acc[fm][fn] = __builtin_amdgcn_mfma_f32_16x16x32_bf16(                 \
            af[fm], __builtin_bit_cast(bf16x8, BCUR[fn]), acc[fm][fn], 0, 0, 0);\
    __builtin_amdgcn_s_setprio(0);                                             \
    __syncthreads();                                                           \
  }

#pragma unroll 1
  for (int s = 0; s < 128; s += 2) {
    GEMM_STEP(s + 1, 16384, 0, bA, bB)      // compute step s (buf0), stage s+1
    GEMM_STEP(s + 2, 0, 16384, bB, bA)      // compute step s+1 (buf1), stage s+2
  }

  // epilogue: deterministic kt-reduction via LDS (stride 66 floats), +x, store
  float* red = (float*)smem;
  if (kt == 1) {
#pragma unroll
    for (int fm = 0; fm < 2; ++fm)
#pragma unroll
      for (int fn = 0; fn < 4; ++fn) {
        int rr = wm * 32 + fm * 16 + lkg * 4;
        int cc = fn * 16 + lrow;
#pragma unroll
        for (int r = 0; r < 4; ++r)
          red[(size_t)(rr + r) * 66 + cc] = acc[fm][fn][r];
      }
  }
  __syncthreads();
  if (kt == 0) {
#pragma unroll
    for (int fm = 0; fm < 2; ++fm)
#pragma unroll
      for (int fn = 0; fn < 4; ++fn) {
        int rr = wm * 32 + fm * 16 + lkg * 4;
        int cc = fn * 16 + lrow;
        size_t gb = (size_t)(mb * 128 + rr) * IN_DIM + nb * 64 + cc;
#pragma unroll
        for (int r = 0; r < 4; ++r) {
          size_t off = gb + (size_t)r * IN_DIM;
          out[off] = acc[fm][fn][r] + red[(size_t)(rr + r) * 66 + cc] + x[off];
        }
      }
  }
}

// ---------------------------------------------------------------------------
// Fallback (round-1 kernel) if ws too small for B_packed (8MB)
// ---------------------------------------------------------------------------
__device__ __forceinline__ void st_b16(char* rb, u32 swz, u32 k0, int c, u16 v) {
  u32 uc = (u32)c;
  u32 byte = (((k0 + (uc >> 3)) ^ swz) << 4) | ((uc & 7u) << 1);
  *(u16*)(rb + byte) = v;
}

__device__ __forceinline__ void stage_a_fb(char* aT, int row, int d, float xv) {
  char* rb = aT + row * 128;
  u32 swz = (u32)(row & 7);
  float xc = fminf(fmaxf(xv, -0.9999f), 0.9999f);
  float tp = __fmaf_rn(xc, 2.5f, 3.0f);
  float fj = floorf(tp);
  int jl = (int)fj;
  float u = tp - fj;
  float u2 = u * u, u3 = u2 * u;
  float vv = 1.0f - u;
  float b0 = vv * vv * vv * (1.0f / 6.0f);
  float b3 = u3 * (1.0f / 6.0f);
  float b1 = __fmaf_rn(0.5f, u3, __fmaf_rn(u2, -1.0f, 2.0f / 3.0f));
  float b2 = 1.0f - b0 - b1 - b3;
  float e = __expf(-xv);
  float sg = __fdividef(xv, 1.0f + e);
  u16 sh = f2bf(sg);
  float shf = __builtin_bit_cast(float, ((u32)sh) << 16);
  u16 slo = f2bf(sg - shf);
  u32 k0 = (u32)d * 2u;
  u32x4 z = {0u, 0u, 0u, 0u};
  *(u32x4*)(rb + ((k0 ^ swz) << 4)) = z;
  u32x4 z2 = {0u, 0u, ((u32)sh) << 16, (u32)slo};
  *(u32x4*)(rb + (((k0 + 1u) ^ swz) << 4)) = z2;
  st_b16(rb, swz, k0, jl + 2, f2bf(b0));
  st_b16(rb, swz, k0, jl + 3, f2bf(b1));
  st_b16(rb, swz, k0, jl + 4, f2bf(b2));
  st_b16(rb, swz, k0, jl + 5, f2bf(b3));
}

__launch_bounds__(512, 2)
__global__ void kan_fused(const float* __restrict__ x,
                          const float* __restrict__ coeffs,
                          const float* __restrict__ bw,
                          float* __restrict__ out) {
  __shared__ __align__(16) char smem[65536];
  const int tid = threadIdx.x;
  const int lane = tid & 63;
  const int wid = tid >> 6;
  const int team = wid >> 2;
  const int wm = (wid >> 1) & 1;
  const int wn = wid & 1;
  const int m0 = wm * 64, n0 = wn * 64;
  const int lrow = lane & 15;
  const int lkg = lane >> 4;
  int s = blockIdx.x;
  int xcd = s & 7;
  int nb = xcd >> 1;
  int mb = (s >> 3) | ((xcd & 1) << 5);
  const int t = tid & 255;
  const int arow = t >> 1;
  const int h = t & 1;
  char* aT = smem + team * 16384;
  char* bT = smem + 32768 + team * 16384;
  const int dim0 = team * 256;
  const float* xptr = x + (size_t)(mb * 128 + arow) * IN_DIM + dim0 + 2 * h;
  const float* cptr = coeffs + ((size_t)((nb * 128 + arow) * IN_DIM) + dim0) * 13 + 26 * h;
  const float* wptr = bw + (size_t)(mb * 0 + nb * 128 + arow) * IN_DIM + dim0 + 2 * h;
  f32x4 acc[4][4];
#pragma unroll
  for (int i = 0; i < 4; ++i)
#pragma unroll
    for (int j = 0; j < 4; ++j) acc[i][j] = (f32x4){0.f, 0.f, 0.f, 0.f};
  float2 xv, wv;
  float2 cv0, cv1, cv2, cv3, cv4, cv5, cv6, cv7, cv8, cv9, cv10, cv11, cv12;
#define PREFETCH(STP)                                                     \
  {                                                                       \
    const float* cp_ = cptr + (STP) * 52;                                 \
    xv = *(const float2*)(xptr + (STP) * 4);                              \
    wv = *(const float2*)(wptr + (STP) * 4);                              \
    cv0 = *(const float2*)(cp_ + 0);   cv1 = *(const float2*)(cp_ + 2);   \
    cv2 = *(const float2*)(cp_ + 4);   cv3 = *(const float2*)(cp_ + 6);   \
    cv4 = *(const float2*)(cp_ + 8);   cv5 = *(const float2*)(cp_ + 10);  \
    cv6 = *(const float2*)(cp_ + 12);  cv7 = *(const float2*)(cp_ + 14);  \
    cv8 = *(const float2*)(cp_ + 16);  cv9 = *(const float2*)(cp_ + 18);  \
    cv10 = *(const float2*)(cp_ + 20); cv11 = *(const float2*)(cp_ + 22); \
    cv12 = *(const float2*)(cp_ + 24);                                    \
  }
  PREFETCH(0)
  for (int st = 0; st < 64; ++st) {
    stage_a_fb(aT, arow, 2 * h + 0, xv.x);
    stage_a_fb(aT, arow, 2 * h + 1, xv.y);
    {
      char* rb = bT + arow * 128;
      u32 swz = (u32)(arow & 7);
      u32 k0 = (u32)(2 * h) * 2u;
      u32x4 lo, hi;
      lo.x = pk2(cv0.x, cv0.y); lo.y = pk2(cv1.x, cv1.y);
      lo.z = pk2(cv2.x, cv2.y); lo.w = pk2(cv3.x, cv3.y);
      hi.x = pk2(cv4.x, cv4.y); hi.y = pk2(cv5.x, cv5.y);
      {
        u16 wb = f2bf(wv.x);
        hi.z = (u32)f2bf(cv6.x) | ((u32)wb << 16);
        hi.w = (u32)wb;
      }
      *(u32x4*)(rb + ((k0 ^ swz) << 4)) = lo;
      *(u32x4*)(rb + (((k0 + 1u) ^ swz) << 4)) = hi;
      lo.x = pk2(cv6.y, cv7.x);  lo.y = pk2(cv7.y, cv8.x);
      lo.z = pk2(cv8.y, cv9.x);  lo.w = pk2(cv9.y, cv10.x);
      hi.x = pk2(cv10.y, cv11.x); hi.y = pk2(cv11.y, cv12.x);
      {
        u16 wb = f2bf(wv.y);
        hi.z = (u32)f2bf(cv12.y) | ((u32)wb << 16);
        hi.w = (u32)wb;
      }
      *(u32x4*)(rb + (((k0 + 2u) ^ swz) << 4)) = lo;
      *(u32x4*)(rb + (((k0 + 3u) ^ swz) << 4)) = hi;
    }
    __syncthreads();
    if (st != 63) { PREFETCH(st + 1) }
    {
      const char* arb = aT + (m0 + lrow) * 128;
      const char* brb = bT + (n0 + lrow) * 128;
      u32 rsw = (u32)(lrow & 7);
#pragma unroll
      for (int ks = 0; ks < 2; ++ks) {
        u32 sl2 = (((u32)(ks * 4) | (u32)lkg) ^ rsw) << 4;
        bf16x8 af[4], bfr2[4];
#pragma unroll
        for (int fm = 0; fm < 4; ++fm)
          af[fm] = __builtin_bit_cast(bf16x8, *(const u32x4*)(arb + fm * 2048 + sl2));
#pragma unroll
        for (int fn = 0; fn < 4; ++fn)
          bfr2[fn] = __builtin_bit_cast(bf16x8, *(const u32x4*)(brb + fn * 2048 + sl2));
#pragma unroll
        for (int fm = 0; fm < 4; ++fm)
#pragma unroll
          for (int fn = 0; fn < 4; ++fn)
            acc[fm][fn] = __builtin_amdgcn_mfma_f32_16x16x32_bf16(
                af[fm], bfr2[fn], acc[fm][fn], 0, 0, 0);
      }
    }
    __syncthreads();
  }
  float* red = (float*)smem;
  if (team == 1) {
#pragma unroll
    for (int fm = 0; fm < 4; ++fm)
#pragma unroll
      for (int fn = 0; fn < 4; ++fn) {
        int rr = m0 + fm * 16 + lkg * 4;
        int cc = n0 + fn * 16 + lrow;
#pragma unroll
        for (int r = 0; r < 4; ++r) red[(rr + r) * 128 + cc] = acc[fm][fn][r];
      }
  }
  __syncthreads();
  if (team == 0) {
#pragma unroll
    for (int fm = 0; fm < 4; ++fm)
#pragma unroll
      for (int fn = 0; fn < 4; ++fn) {
        int rr = m0 + fm * 16 + lkg * 4;
        int ccol = n0 + fn * 16 + lrow;
        int grow = mb * 128 + rr;
        int gcol = nb * 128 + ccol;
#pragma unroll
        for (int r = 0; r < 4; ++r) {
          float v = acc[fm][fn][r] + red[(rr + r) * 128 + ccol] +
                    x[(size_t)(grow + r) * IN_DIM + gcol];
          out[(size_t)(grow + r) * IN_DIM + gcol] = v;
        }
      }
  }
}

extern "C" void kernel_launch(void* const* d_in, const int* in_sizes, int n_in,
                              void* d_out, int out_size, void* d_ws, size_t ws_size,
                              hipStream_t stream) {
  const float* x = (const float*)d_in[0];
  const float* coeffs = (const float*)d_in[1];
  const float* bw = (const float*)d_in[2];
  float* out = (float*)d_out;
  if (ws_size >= (size_t)512 * 16384) {  // 8 MB for B_packed
    char* Bp = (char*)d_ws;
    hipLaunchKernelGGL(pack_b, dim3(1024), dim3(256), 0, stream, coeffs, bw, Bp);
    hipLaunchKernelGGL(kan_gemm, dim3(512), dim3(512), 0, stream, x, Bp, out);
  } else {
    hipLaunchKernelGGL(kan_fused, dim3(256), dim3(512), 0, stream, x, coeffs, bw, out);
  }
}

// Round 5
// 98.109 us; speedup vs baseline: 1.3962x; 1.3962x over previous
//
#include <hip/hip_runtime.h>
#include <stdint.h>

typedef unsigned int u32;
typedef unsigned short u16;
typedef unsigned long long u64;
typedef __bf16 bf16x8 __attribute__((ext_vector_type(8)));
typedef float f32x4 __attribute__((ext_vector_type(4)));
typedef u32 u32x4 __attribute__((ext_vector_type(4)));

#define IN_DIM 512

__device__ __forceinline__ u16 bfr(float f) {
  __bf16 h = (__bf16)f;
  return __builtin_bit_cast(u16, h);
}
__device__ __forceinline__ u16 f2bf(float f) {
  u32 u = __builtin_bit_cast(u32, f);
  u += 0x7fffu + ((u >> 16) & 1u);
  return (u16)(u >> 16);
}
__device__ __forceinline__ u32 pk2(float a, float b) {
  return (u32)f2bf(a) | ((u32)f2bf(b) << 16);
}

// ---------------------------------------------------------------------------
// pack_b: B packed in MFMA-fragment order (L2->VGPR direct in the GEMM).
// Chunk(nbp, s, cb, ks) = 64 lanes x 16B; lane l holds
//   col = nbp*128 + cb*16 + (l&15), kexp = s*64 + ks*32 + (l>>4)*8 .. +7
// Per (col,dim) 16 slots: 0..12 coeffs, 13=W, 14=W, 15=0.
// ---------------------------------------------------------------------------
__global__ void pack_b(const float* __restrict__ coeffs,
                       const float* __restrict__ bw,
                       char* __restrict__ Bp) {
  __shared__ float stage[64][56];
  const int tid = threadIdx.x;
  const int q = tid & 3, g = tid >> 2;
  const int id = blockIdx.x * 64 + g;          // (col, s) pair
  const int col = id >> 7, s = id & 127;
  const float* cbase = coeffs + ((size_t)col * IN_DIM + s * 4) * 13;
#pragma unroll
  for (int j = 0; j < 3; ++j) {
    int ch = q + j * 4;
    float4 v = *(const float4*)(cbase + ch * 4);
    stage[g][ch * 4 + 0] = v.x; stage[g][ch * 4 + 1] = v.y;
    stage[g][ch * 4 + 2] = v.z; stage[g][ch * 4 + 3] = v.w;
  }
  if (q == 0) {
    float4 v = *(const float4*)(cbase + 48);
    stage[g][48] = v.x; stage[g][49] = v.y; stage[g][50] = v.z; stage[g][51] = v.w;
  }
  if (q == 1) {
    float4 v = *(const float4*)(bw + (size_t)col * IN_DIM + s * 4);
    stage[g][52] = v.x; stage[g][53] = v.y; stage[g][54] = v.z; stage[g][55] = v.w;
  }
  __syncthreads();
  const int nbp = col >> 7, cb = (col >> 4) & 7, cl = col & 15;
  char* base = Bp + (((size_t)(nbp * 128 + s) * 8 + cb) * 2) * 1024;
#pragma unroll
  for (int r = 0; r < 2; ++r) {
    int idx = q * 2 + r;
    int h = idx & 1;
    int dd = idx >> 1;              // dim-in-step 0..3
    int ks = dd >> 1;
    const float* sf = &stage[g][dd * 13];
    float w = stage[g][52 + dd];
    u16 hh[8];
#pragma unroll
    for (int c = 0; c < 8; ++c) {
      int slot = h * 8 + c;
      float v = slot < 13 ? sf[slot] : (slot < 15 ? w : 0.0f);
      hh[c] = bfr(v);
    }
    u32x4 o;
    o.x = (u32)hh[0] | ((u32)hh[1] << 16);
    o.y = (u32)hh[2] | ((u32)hh[3] << 16);
    o.z = (u32)hh[4] | ((u32)hh[5] << 16);
    o.w = (u32)hh[6] | ((u32)hh[7] << 16);
    int lanei = cl + 16 * (2 * (dd & 1) + h);
    *(u32x4*)(base + (size_t)ks * 1024 + lanei * 16) = o;
  }
}

// ---------------------------------------------------------------------------
// A expansion: one x -> 16 bf16 K-slots as two swizzled ds_write_b128.
// ---------------------------------------------------------------------------
__device__ __forceinline__ void expandA(float xv, char* rb, u32 swz, u32 k0) {
  float xc = fminf(fmaxf(xv, -0.9999f), 0.9999f);
  float tp = __fmaf_rn(xc, 2.5f, 3.0f);
  float fj = floorf(tp);
  int jl = (int)fj;  // 0..5
  float u = tp - fj;
  float u2 = u * u, u3 = u2 * u;
  float vv = 1.0f - u;
  float b0 = vv * vv * vv * (1.0f / 6.0f);
  float b3 = u3 * (1.0f / 6.0f);
  float b1 = __fmaf_rn(0.5f, u3, __fmaf_rn(u2, -1.0f, 2.0f / 3.0f));
  float b2 = 1.0f - b0 - b1 - b3;
  float e = __expf(-xv);
  float sg = __fdividef(xv, 1.0f + e);
  u16 sh = bfr(sg);
  float shf = __builtin_bit_cast(float, ((u32)sh) << 16);
  u16 sl = bfr(sg - shf);
  u32 pk01 = (u32)bfr(b0) | ((u32)bfr(b1) << 16);
  u32 pk23 = (u32)bfr(b2) | ((u32)bfr(b3) << 16);
  u64 v = (u64)pk01 | (((u64)pk23) << 32);
  int sstart = jl + 2;       // 2..7
  int qa = sstart >> 2;
  int shn = (sstart & 3) << 4;
  u64 lo = v << shn;
  u64 hi = shn ? (v >> (64 - shn)) : 0ull;
  u64 q0 = qa ? 0ull : lo;
  u64 q1 = qa ? lo : hi;
  u64 q2 = qa ? hi : 0ull;
  u64 q3 = (u64)(((u32)sh) << 16) | (((u64)(u32)sl) << 32);
  u32x4 c0, c1;
  c0.x = (u32)q0; c0.y = (u32)(q0 >> 32); c0.z = (u32)q1; c0.w = (u32)(q1 >> 32);
  c1.x = (u32)q2; c1.y = (u32)(q2 >> 32); c1.z = (u32)q3; c1.w = (u32)(q3 >> 32);
  *(u32x4*)(rb + ((k0 ^ swz) << 4)) = c0;
  *(u32x4*)(rb + (((k0 + 1u) ^ swz) << 4)) = c1;
}

// ---------------------------------------------------------------------------
// Main GEMM: BM=BN=128, grid 256 (1/CU), 512 threads = 8 waves:
// 2x2 spatial (64x64 wave tiles) x 2-way K-split. A through LDS (dbuf),
// B-frags L2->regs (reg dbuf). KEY: barriers are raw s_barrier with ONLY
// lgkmcnt(0) drained, so B/x prefetch loads stay in flight across steps
// (no vmcnt(0) drain per step = no per-step HBM/L2 latency serialization).
// ---------------------------------------------------------------------------
__launch_bounds__(512, 2)
__global__ void kan_gemm(const float* __restrict__ x,
                         const char* __restrict__ Bp,
                         float* __restrict__ out) {
  __shared__ __align__(16) char smem[128 * 129 * 4];  // A dbuf 32KB | red 66KB

  const int tid = threadIdx.x;
  const int lane = tid & 63;
  const int wid = tid >> 6;
  const int kt = wid >> 2;             // K-split team
  const int wm = (wid >> 1) & 1, wn = wid & 1;
  const int lrow = lane & 15, lkg = lane >> 4;

  int s0 = blockIdx.x;
  int xcd = s0 & 7;
  int nb = xcd >> 1;                   // XCD pair owns one 2MB B panel in L2
  int mb = ((s0 >> 3) << 1) | (xcd & 1);  // 0..63

  // A expansion: 1 value/thread/step
  const int arow = tid >> 2, ad = tid & 3;
  const u32 aswz = (u32)(arow & 7);
  const u32 ak0 = (u32)(ad * 2);
  const float* xp = x + (size_t)(mb * 128 + arow) * IN_DIM + ad;

  const char* bptr = Bp + (((size_t)(nb * 128) * 8 + wn * 4) * 2 + kt) * 1024 + (size_t)lane * 16;

  f32x4 acc[4][4];
#pragma unroll
  for (int i = 0; i < 4; ++i)
#pragma unroll
    for (int j = 0; j < 4; ++j) acc[i][j] = (f32x4){0.f, 0.f, 0.f, 0.f};

  u32x4 bA[4], bB[4];
  // prologue: expand step 0 into buf0, load B-frags for step 0, x lookahead 2
  expandA(xp[0], smem + arow * 128, aswz, ak0);
#pragma unroll
  for (int fn = 0; fn < 4; ++fn)
    bA[fn] = *(const u32x4*)(bptr + fn * 2048);
  float xn1 = xp[4];     // x for step 1
  float xn2 = xp[8];     // x for step 2
  __syncthreads();       // one-time full drain, fine

  const char* arb_base = smem + (wm * 64 + lrow) * 128;
  const u32 asl = (((u32)(kt * 4) | (u32)lkg) ^ (u32)(lrow & 7)) << 4;

  // SN = step being STAGED (current compute step = SN-1).
#define GEMM_STEP(SN, NXT_OFF, CUR_OFF, BCUR, BNXT)                            \
  {                                                                            \
    /* 1) A-frags of current step: ds_read latency hides under expand VALU */  \
    bf16x8 af[4];                                                              \
    _Pragma("unroll")                                                          \
    for (int fm = 0; fm < 4; ++fm)                                             \
      af[fm] = __builtin_bit_cast(bf16x8,                                      \
          *(const u32x4*)(arb_base + (CUR_OFF) + fm * 2048 + asl));            \
    /* 2) issue next B-frags + x two steps ahead (stay in flight, no drain) */ \
    int sl_ = (SN) < 128 ? (SN) : 127;                                         \
    _Pragma("unroll")                                                          \
    for (int fn = 0; fn < 4; ++fn)                                             \
      BNXT[fn] = *(const u32x4*)(bptr + (size_t)sl_ * 16384 + fn * 2048);      \
    float xload = xp[((SN) + 2 < 128 ? (SN) + 2 : 127) * 4];                   \
    /* 3) expand step SN into the other buffer */                              \
    if ((SN) < 128) expandA(xn1, smem + (NXT_OFF) + arow * 128, aswz, ak0);    \
    xn1 = xn2; xn2 = xload;                                                    \
    /* 4) MFMA on current step */                                              \
    __builtin_amdgcn_s_setprio(1);                                             \
    _Pragma("unroll")                                                          \
    for (int fm = 0; fm < 4; ++fm)                                             \
      _Pragma("unroll")                                                        \
      for (int fn = 0; fn < 4; ++fn)                                           \
        acc[fm][fn] = __builtin_amdgcn_mfma_f32_16x16x32_bf16(                 \
            af[fm], __builtin_bit_cast(bf16x8, BCUR[fn]), acc[fm][fn], 0, 0, 0);\
    __builtin_amdgcn_s_setprio(0);                                             \
    /* 5) barrier draining ONLY lgkm (ds_writes visible); vmem stays queued */ \
    asm volatile("s_waitcnt lgkmcnt(0)" ::: "memory");                         \
    __builtin_amdgcn_s_barrier();                                              \
  }

#pragma unroll 1
  for (int s = 0; s < 128; s += 2) {
    GEMM_STEP(s + 1, 16384, 0, bA, bB)      // compute step s (buf0), stage s+1
    GEMM_STEP(s + 2, 0, 16384, bB, bA)      // compute step s+1 (buf1), stage s+2
  }

  __syncthreads();  // full drain before smem reuse

  // epilogue: deterministic cross-team reduction via LDS (stride 129 floats)
  float* red = (float*)smem;
  if (kt == 1) {
#pragma unroll
    for (int fm = 0; fm < 4; ++fm)
#pragma unroll
      for (int fn = 0; fn < 4; ++fn) {
        int rr = wm * 64 + fm * 16 + lkg * 4;
        int cc = wn * 64 + fn * 16 + lrow;
#pragma unroll
        for (int r = 0; r < 4; ++r)
          red[(size_t)(rr + r) * 129 + cc] = acc[fm][fn][r];
      }
  }
  __syncthreads();
  if (kt == 0) {
#pragma unroll
    for (int fm = 0; fm < 4; ++fm)
#pragma unroll
      for (int fn = 0; fn < 4; ++fn) {
        int rr = wm * 64 + fm * 16 + lkg * 4;
        int cc = wn * 64 + fn * 16 + lrow;
        size_t gb = (size_t)(mb * 128 + rr) * IN_DIM + nb * 128 + cc;
#pragma unroll
        for (int r = 0; r < 4; ++r) {
          size_t off = gb + (size_t)r * IN_DIM;
          out[off] = acc[fm][fn][r] + red[(size_t)(rr + r) * 129 + cc] + x[off];
        }
      }
  }
}

// ---------------------------------------------------------------------------
// Fallback (round-1 kernel) if ws too small for B_packed (8MB)
// ---------------------------------------------------------------------------
__device__ __forceinline__ void st_b16(char* rb, u32 swz, u32 k0, int c, u16 v) {
  u32 uc = (u32)c;
  u32 byte = (((k0 + (uc >> 3)) ^ swz) << 4) | ((uc & 7u) << 1);
  *(u16*)(rb + byte) = v;
}

__device__ __forceinline__ void stage_a_fb(char* aT, int row, int d, float xv) {
  char* rb = aT + row * 128;
  u32 swz = (u32)(row & 7);
  float xc = fminf(fmaxf(xv, -0.9999f), 0.9999f);
  float tp = __fmaf_rn(xc, 2.5f, 3.0f);
  float fj = floorf(tp);
  int jl = (int)fj;
  float u = tp - fj;
  float u2 = u * u, u3 = u2 * u;
  float vv = 1.0f - u;
  float b0 = vv * vv * vv * (1.0f / 6.0f);
  float b3 = u3 * (1.0f / 6.0f);
  float b1 = __fmaf_rn(0.5f, u3, __fmaf_rn(u2, -1.0f, 2.0f / 3.0f));
  float b2 = 1.0f - b0 - b1 - b3;
  float e = __expf(-xv);
  float sg = __fdividef(xv, 1.0f + e);
  u16 sh = f2bf(sg);
  float shf = __builtin_bit_cast(float, ((u32)sh) << 16);
  u16 slo = f2bf(sg - shf);
  u32 k0 = (u32)d * 2u;
  u32x4 z = {0u, 0u, 0u, 0u};
  *(u32x4*)(rb + ((k0 ^ swz) << 4)) = z;
  u32x4 z2 = {0u, 0u, ((u32)sh) << 16, (u32)slo};
  *(u32x4*)(rb + (((k0 + 1u) ^ swz) << 4)) = z2;
  st_b16(rb, swz, k0, jl + 2, f2bf(b0));
  st_b16(rb, swz, k0, jl + 3, f2bf(b1));
  st_b16(rb, swz, k0, jl + 4, f2bf(b2));
  st_b16(rb, swz, k0, jl + 5, f2bf(b3));
}

__launch_bounds__(512, 2)
__global__ void kan_fused(const float* __restrict__ x,
                          const float* __restrict__ coeffs,
                          const float* __restrict__ bw,
                          float* __restrict__ out) {
  __shared__ __align__(16) char smem[65536];
  const int tid = threadIdx.x;
  const int lane = tid & 63;
  const int wid = tid >> 6;
  const int team = wid >> 2;
  const int wm = (wid >> 1) & 1;
  const int wn = wid & 1;
  const int m0 = wm * 64, n0 = wn * 64;
  const int lrow = lane & 15;
  const int lkg = lane >> 4;
  int s = blockIdx.x;
  int xcd = s & 7;
  int nb = xcd >> 1;
  int mb = (s >> 3) | ((xcd & 1) << 5);
  const int t = tid & 255;
  const int arow = t >> 1;
  const int h = t & 1;
  char* aT = smem + team * 16384;
  char* bT = smem + 32768 + team * 16384;
  const int dim0 = team * 256;
  const float* xptr = x + (size_t)(mb * 128 + arow) * IN_DIM + dim0 + 2 * h;
  const float* cptr = coeffs + ((size_t)((nb * 128 + arow) * IN_DIM) + dim0) * 13 + 26 * h;
  const float* wptr = bw + (size_t)(nb * 128 + arow) * IN_DIM + dim0 + 2 * h;
  f32x4 acc[4][4];
#pragma unroll
  for (int i = 0; i < 4; ++i)
#pragma unroll
    for (int j = 0; j < 4; ++j) acc[i][j] = (f32x4){0.f, 0.f, 0.f, 0.f};
  float2 xv, wv;
  float2 cv0, cv1, cv2, cv3, cv4, cv5, cv6, cv7, cv8, cv9, cv10, cv11, cv12;
#define PREFETCH(STP)                                                     \
  {                                                                       \
    const float* cp_ = cptr + (STP) * 52;                                 \
    xv = *(const float2*)(xptr + (STP) * 4);                              \
    wv = *(const float2*)(wptr + (STP) * 4);                              \
    cv0 = *(const float2*)(cp_ + 0);   cv1 = *(const float2*)(cp_ + 2);   \
    cv2 = *(const float2*)(cp_ + 4);   cv3 = *(const float2*)(cp_ + 6);   \
    cv4 = *(const float2*)(cp_ + 8);   cv5 = *(const float2*)(cp_ + 10);  \
    cv6 = *(const float2*)(cp_ + 12);  cv7 = *(const float2*)(cp_ + 14);  \
    cv8 = *(const float2*)(cp_ + 16);  cv9 = *(const float2*)(cp_ + 18);  \
    cv10 = *(const float2*)(cp_ + 20); cv11 = *(const float2*)(cp_ + 22); \
    cv12 = *(const float2*)(cp_ + 24);                                    \
  }
  PREFETCH(0)
  for (int st = 0; st < 64; ++st) {
    stage_a_fb(aT, arow, 2 * h + 0, xv.x);
    stage_a_fb(aT, arow, 2 * h + 1, xv.y);
    {
      char* rb = bT + arow * 128;
      u32 swz = (u32)(arow & 7);
      u32 k0 = (u32)(2 * h) * 2u;
      u32x4 lo, hi;
      lo.x = pk2(cv0.x, cv0.y); lo.y = pk2(cv1.x, cv1.y);
      lo.z = pk2(cv2.x, cv2.y); lo.w = pk2(cv3.x, cv3.y);
      hi.x = pk2(cv4.x, cv4.y); hi.y = pk2(cv5.x, cv5.y);
      {
        u16 wb = f2bf(wv.x);
        hi.z = (u32)f2bf(cv6.x) | ((u32)wb << 16);
        hi.w = (u32)wb;
      }
      *(u32x4*)(rb + ((k0 ^ swz) << 4)) = lo;
      *(u32x4*)(rb + (((k0 + 1u) ^ swz) << 4)) = hi;
      lo.x = pk2(cv6.y, cv7.x);  lo.y = pk2(cv7.y, cv8.x);
      lo.z = pk2(cv8.y, cv9.x);  lo.w = pk2(cv9.y, cv10.x);
      hi.x = pk2(cv10.y, cv11.x); hi.y = pk2(cv11.y, cv12.x);
      {
        u16 wb = f2bf(wv.y);
        hi.z = (u32)f2bf(cv12.y) | ((u32)wb << 16);
        hi.w = (u32)wb;
      }
      *(u32x4*)(rb + (((k0 + 2u) ^ swz) << 4)) = lo;
      *(u32x4*)(rb + (((k0 + 3u) ^ swz) << 4)) = hi;
    }
    __syncthreads();
    if (st != 63) { PREFETCH(st + 1) }
    {
      const char* arb = aT + (m0 + lrow) * 128;
      const char* brb = bT + (n0 + lrow) * 128;
      u32 rsw = (u32)(lrow & 7);
#pragma unroll
      for (int ks = 0; ks < 2; ++ks) {
        u32 sl2 = (((u32)(ks * 4) | (u32)lkg) ^ rsw) << 4;
        bf16x8 af[4], bfr2[4];
#pragma unroll
        for (int fm = 0; fm < 4; ++fm)
          af[fm] = __builtin_bit_cast(bf16x8, *(const u32x4*)(arb + fm * 2048 + sl2));
#pragma unroll
        for (int fn = 0; fn < 4; ++fn)
          bfr2[fn] = __builtin_bit_cast(bf16x8, *(const u32x4*)(brb + fn * 2048 + sl2));
#pragma unroll
        for (int fm = 0; fm < 4; ++fm)
#pragma unroll
          for (int fn = 0; fn < 4; ++fn)
            acc[fm][fn] = __builtin_amdgcn_mfma_f32_16x16x32_bf16(
                af[fm], bfr2[fn], acc[fm][fn], 0, 0, 0);
      }
    }
    __syncthreads();
  }
  float* red = (float*)smem;
  if (team == 1) {
#pragma unroll
    for (int fm = 0; fm < 4; ++fm)
#pragma unroll
      for (int fn = 0; fn < 4; ++fn) {
        int rr = m0 + fm * 16 + lkg * 4;
        int cc = n0 + fn * 16 + lrow;
#pragma unroll
        for (int r = 0; r < 4; ++r) red[(rr + r) * 128 + cc] = acc[fm][fn][r];
      }
  }
  __syncthreads();
  if (team == 0) {
#pragma unroll
    for (int fm = 0; fm < 4; ++fm)
#pragma unroll
      for (int fn = 0; fn < 4; ++fn) {
        int rr = m0 + fm * 16 + lkg * 4;
        int ccol = n0 + fn * 16 + lrow;
        int grow = mb * 128 + rr;
        int gcol = nb * 128 + ccol;
#pragma unroll
        for (int r = 0; r < 4; ++r) {
          float v = acc[fm][fn][r] + red[(rr + r) * 128 + ccol] +
                    x[(size_t)(grow + r) * IN_DIM + gcol];
          out[(size_t)(grow + r) * IN_DIM + gcol] = v;
        }
      }
  }
}

extern "C" void kernel_launch(void* const* d_in, const int* in_sizes, int n_in,
                              void* d_out, int out_size, void* d_ws, size_t ws_size,
                              hipStream_t stream) {
  const float* x = (const float*)d_in[0];
  const float* coeffs = (const float*)d_in[1];
  const float* bw = (const float*)d_in[2];
  float* out = (float*)d_out;
  if (ws_size >= (size_t)512 * 16384) {  // 8 MB for B_packed
    char* Bp = (char*)d_ws;
    hipLaunchKernelGGL(pack_b, dim3(1024), dim3(256), 0, stream, coeffs, bw, Bp);
    hipLaunchKernelGGL(kan_gemm, dim3(256), dim3(512), 0, stream, x, Bp, out);
  } else {
    hipLaunchKernelGGL(kan_fused, dim3(256), dim3(512), 0, stream, x, coeffs, bw, out);
  }
}